// Round 7
// baseline (137.728 us; speedup 1.0000x reference)
//
#include <hip/hip_runtime.h>

#define DEG 32
#define HID 32
#define CIN 8

typedef float v2f __attribute__((ext_vector_type(2)));

// gelu(x) = x - x * rcp(1 + exp2( x*(A + B*x^2) ))   [jax tanh-approx, refactored]
#define GELU_A ((float)(2.0 * 1.4426950408889634 * 0.7978845608028654))
#define GELU_B ((float)(2.0 * 1.4426950408889634 * 0.7978845608028654 * 0.044715))

__device__ __forceinline__ unsigned f2bf(float f) {   // fp32 -> bf16 (RNE)
    unsigned b = __float_as_uint(f);
    return (b + 0x7fffu + ((b >> 16) & 1u)) >> 16;
}

// Phase 1: u16[n] = bf16(x[n] @ W1[:8])  (row = 64 B)  and
//          v32[n] = fp32(b1 + x[n] @ W1[8:])  (row = 128 B).
__global__ __launch_bounds__(256) void precompute_uv16(
    const float* __restrict__ x, const float* __restrict__ W1,
    const float* __restrict__ b1, unsigned* __restrict__ u16,
    float* __restrict__ v32, int N) {
    int tid = blockIdx.x * 256 + threadIdx.x;
    if (tid >= N * 4) return;
    int n = tid >> 2;
    int q = tid & 3;                        // channels q*8 .. q*8+7
    const float4* xp = (const float4*)(x + (size_t)n * CIN);
    float4 a = xp[0], b = xp[1];
    float xv[8] = {a.x, a.y, a.z, a.w, b.x, b.y, b.z, b.w};
    float4 b1a = *(const float4*)(b1 + q * 8);
    float4 b1b = *(const float4*)(b1 + q * 8 + 4);
    float su[8] = {0.f, 0.f, 0.f, 0.f, 0.f, 0.f, 0.f, 0.f};
    float sv[8] = {b1a.x, b1a.y, b1a.z, b1a.w, b1b.x, b1b.y, b1b.z, b1b.w};
#pragma unroll
    for (int k = 0; k < 8; ++k) {
        float4 u0 = *(const float4*)(W1 + k * HID + q * 8);
        float4 u1 = *(const float4*)(W1 + k * HID + q * 8 + 4);
        float4 v0 = *(const float4*)(W1 + (k + 8) * HID + q * 8);
        float4 v1 = *(const float4*)(W1 + (k + 8) * HID + q * 8 + 4);
        float xk = xv[k];
        su[0] = fmaf(xk, u0.x, su[0]); su[1] = fmaf(xk, u0.y, su[1]);
        su[2] = fmaf(xk, u0.z, su[2]); su[3] = fmaf(xk, u0.w, su[3]);
        su[4] = fmaf(xk, u1.x, su[4]); su[5] = fmaf(xk, u1.y, su[5]);
        su[6] = fmaf(xk, u1.z, su[6]); su[7] = fmaf(xk, u1.w, su[7]);
        sv[0] = fmaf(xk, v0.x, sv[0]); sv[1] = fmaf(xk, v0.y, sv[1]);
        sv[2] = fmaf(xk, v0.z, sv[2]); sv[3] = fmaf(xk, v0.w, sv[3]);
        sv[4] = fmaf(xk, v1.x, sv[4]); sv[5] = fmaf(xk, v1.y, sv[5]);
        sv[6] = fmaf(xk, v1.z, sv[6]); sv[7] = fmaf(xk, v1.w, sv[7]);
    }
    uint4 o;
    o.x = f2bf(su[0]) | (f2bf(su[1]) << 16);
    o.y = f2bf(su[2]) | (f2bf(su[3]) << 16);
    o.z = f2bf(su[4]) | (f2bf(su[5]) << 16);
    o.w = f2bf(su[6]) | (f2bf(su[7]) << 16);
    *(uint4*)(u16 + (size_t)n * 16 + q * 4) = o;
    *(float4*)(v32 + (size_t)n * HID + q * 8)     = make_float4(sv[0], sv[1], sv[2], sv[3]);
    *(float4*)(v32 + (size_t)n * HID + q * 8 + 4) = make_float4(sv[4], sv[5], sv[6], sv[7]);
}

// Phase 2: TWO NODES PER HALF-WAVE (16 nodes / 256-block), register-level
// double buffering: issue A's 8 gathers, then B's 8, compute A (B in flight),
// compute B. Within a 32-lane half: ep = l5>>3 (edge group), c4 = l5&7
// (channel quad 4c4..4c4+3, dwordx2 bf16 gather).
__global__ __launch_bounds__(256, 5) void git_main5(
    const unsigned* __restrict__ u16, const float* __restrict__ v32,
    const float* __restrict__ wgt, const float* __restrict__ W2,
    const float* __restrict__ b2, const int* __restrict__ nbr,
    float* __restrict__ out, int N) {
    __shared__ float sW2[HID * HID];
    __shared__ float sb2[HID];
    __shared__ int2  sp[8 * 64];       // 8 half-slots x 64 edges (A: 0..31, B: 32..63)
    __shared__ float sg[16 * HID];     // per-node reduced g

    int t = threadIdx.x;
#pragma unroll
    for (int i = 0; i < 4; ++i) sW2[t + i * 256] = W2[t + i * 256];
    if (t < HID) sb2[t] = b2[t];

    int hs = t >> 5;                   // half-wave slot 0..7
    int l5 = t & 31;
    int ep = l5 >> 3;                  // edge group 0..3
    int c4 = l5 & 7;                   // channel quad
    int nA = blockIdx.x * 16 + hs * 2;
    int nB = nA + 1;
    bool vA = nA < N, vB = nB < N;
    int ncA = vA ? nA : (N - 1);
    int ncB = vB ? nB : (N - 1);

    // stage (u-row byte offset, weight) for both nodes (wave-internal LDS)
    int   jA = nbr[ncA * DEG + l5];                // coalesced 128B per half
    int   jB = nbr[ncB * DEG + l5];
    float wA = wgt[jA];                            // 400 KB table, cache-hot
    float wB = wgt[jB];
    sp[hs * 64 + l5]      = make_int2(jA << 6, __float_as_int(wA));
    sp[hs * 64 + 32 + l5] = make_int2(jB << 6, __float_as_int(wB));

    // ws = sum of 32 neighbor weights per node (butterfly within the half)
    float wsA = wA;
    wsA += __shfl_xor(wsA, 1);  wsA += __shfl_xor(wsA, 2);
    wsA += __shfl_xor(wsA, 4);  wsA += __shfl_xor(wsA, 8);
    wsA += __shfl_xor(wsA, 16);
    float wsB = wB;
    wsB += __shfl_xor(wsB, 1);  wsB += __shfl_xor(wsB, 2);
    wsB += __shfl_xor(wsB, 4);  wsB += __shfl_xor(wsB, 8);
    wsB += __shfl_xor(wsB, 16);

    // v for this lane's 4 channels, both nodes (one dwordx4 each)
    float4 vvA = *(const float4*)(v32 + (size_t)ncA * HID + c4 * 4);
    float4 vvB = *(const float4*)(v32 + (size_t)ncB * HID + c4 * 4);
    v2f vbA0 = {vvA.x, vvA.y}, vbA1 = {vvA.z, vvA.w};
    v2f vbB0 = {vvB.x, vvB.y}, vbB1 = {vvB.z, vvB.w};

    // ---- issue ALL 16 gathers (8 per node) before any gelu ----
    const char* ub = (const char*)u16;
    int myb = c4 * 8;
    const int2* pA = &sp[hs * 64 + ep * 8];
    const int2* pB = pA + 32;
    uint2 bitsA[8], bitsB[8];
    float wjA[8], wjB[8];
#pragma unroll
    for (int e = 0; e < 8; ++e) {
        int2 p  = pA[e];                            // ds_read_b64, imm offset
        wjA[e]  = __int_as_float(p.y);
        bitsA[e] = *(const uint2*)(ub + (unsigned)(p.x + myb));
    }
#pragma unroll
    for (int e = 0; e < 8; ++e) {
        int2 p  = pB[e];
        wjB[e]  = __int_as_float(p.y);
        bitsB[e] = *(const uint2*)(ub + (unsigned)(p.x + myb));
    }

    // ---- compute A (B's loads still in flight) ----
    v2f gA0 = {0.f, 0.f}, gA1 = {0.f, 0.f};
#pragma unroll
    for (int e = 0; e < 8; ++e) {
        unsigned ba = bitsA[e].x, bb = bitsA[e].y;
        v2f uf0, uf1;
        uf0.x = __uint_as_float(ba << 16);
        uf0.y = __uint_as_float(ba & 0xffff0000u);
        uf1.x = __uint_as_float(bb << 16);
        uf1.y = __uint_as_float(bb & 0xffff0000u);
        v2f t0 = uf0 + vbA0, t1 = uf1 + vbA1;
        v2f x20 = t0 * t0,  x21 = t1 * t1;
        v2f z0 = t0 * (x20 * GELU_B + GELU_A);
        v2f z1 = t1 * (x21 * GELU_B + GELU_A);
        v2f e0, e1;
        e0.x = __builtin_amdgcn_exp2f(z0.x);  e0.y = __builtin_amdgcn_exp2f(z0.y);
        e1.x = __builtin_amdgcn_exp2f(z1.x);  e1.y = __builtin_amdgcn_exp2f(z1.y);
        v2f d0 = e0 + 1.0f, d1 = e1 + 1.0f;
        v2f r0, r1;
        r0.x = __builtin_amdgcn_rcpf(d0.x);  r0.y = __builtin_amdgcn_rcpf(d0.y);
        r1.x = __builtin_amdgcn_rcpf(d1.x);  r1.y = __builtin_amdgcn_rcpf(d1.y);
        gA0 += wjA[e] * (t0 - t0 * r0);             // gelu; exact +/-inf limits
        gA1 += wjA[e] * (t1 - t1 * r1);
    }

    // ---- compute B ----
    v2f gB0 = {0.f, 0.f}, gB1 = {0.f, 0.f};
#pragma unroll
    for (int e = 0; e < 8; ++e) {
        unsigned ba = bitsB[e].x, bb = bitsB[e].y;
        v2f uf0, uf1;
        uf0.x = __uint_as_float(ba << 16);
        uf0.y = __uint_as_float(ba & 0xffff0000u);
        uf1.x = __uint_as_float(bb << 16);
        uf1.y = __uint_as_float(bb & 0xffff0000u);
        v2f t0 = uf0 + vbB0, t1 = uf1 + vbB1;
        v2f x20 = t0 * t0,  x21 = t1 * t1;
        v2f z0 = t0 * (x20 * GELU_B + GELU_A);
        v2f z1 = t1 * (x21 * GELU_B + GELU_A);
        v2f e0, e1;
        e0.x = __builtin_amdgcn_exp2f(z0.x);  e0.y = __builtin_amdgcn_exp2f(z0.y);
        e1.x = __builtin_amdgcn_exp2f(z1.x);  e1.y = __builtin_amdgcn_exp2f(z1.y);
        v2f d0 = e0 + 1.0f, d1 = e1 + 1.0f;
        v2f r0, r1;
        r0.x = __builtin_amdgcn_rcpf(d0.x);  r0.y = __builtin_amdgcn_rcpf(d0.y);
        r1.x = __builtin_amdgcn_rcpf(d1.x);  r1.y = __builtin_amdgcn_rcpf(d1.y);
        gB0 += wjB[e] * (t0 - t0 * r0);
        gB1 += wjB[e] * (t1 - t1 * r1);
    }

    // reduce over the 4 edge groups (xor 8,16 stay within each 32-half)
    gA0.x += __shfl_xor(gA0.x, 8);   gA0.y += __shfl_xor(gA0.y, 8);
    gA1.x += __shfl_xor(gA1.x, 8);   gA1.y += __shfl_xor(gA1.y, 8);
    gB0.x += __shfl_xor(gB0.x, 8);   gB0.y += __shfl_xor(gB0.y, 8);
    gB1.x += __shfl_xor(gB1.x, 8);   gB1.y += __shfl_xor(gB1.y, 8);
    gA0.x += __shfl_xor(gA0.x, 16);  gA0.y += __shfl_xor(gA0.y, 16);
    gA1.x += __shfl_xor(gA1.x, 16);  gA1.y += __shfl_xor(gA1.y, 16);
    gB0.x += __shfl_xor(gB0.x, 16);  gB0.y += __shfl_xor(gB0.y, 16);
    gB1.x += __shfl_xor(gB1.x, 16);  gB1.y += __shfl_xor(gB1.y, 16);

    if (l5 < 8) {                    // ep==0 lanes publish reduced g for both nodes
        *(float4*)(&sg[(hs * 2)     * HID + c4 * 4]) = make_float4(gA0.x, gA0.y, gA1.x, gA1.y);
        *(float4*)(&sg[(hs * 2 + 1) * HID + c4 * 4]) = make_float4(gB0.x, gB0.y, gB1.x, gB1.y);
    }

    __syncthreads();                 // sW2 (cross-wave) + sg ready

    // ---- hoisted second linear, once per node ----
    int oc2 = l5 & 15;               // output pair 2oc2, 2oc2+1
    int s   = l5 >> 4;               // h-half
#pragma unroll
    for (int r = 0; r < 2; ++r) {
        int ni = hs * 2 + r;
        int node = blockIdx.x * 16 + ni;
        const float* sgrow  = &sg[ni * HID + s * 16];
        const float* w2base = &sW2[(s * 16) * HID + oc2 * 2];
        v2f acc = {0.f, 0.f};
#pragma unroll
        for (int hh = 0; hh < 8; ++hh) {
            v2f gp = *(const v2f*)(sgrow + hh * 2);            // broadcast
            v2f wa = *(const v2f*)(w2base + (hh * 2) * HID);
            v2f wb = *(const v2f*)(w2base + (hh * 2 + 1) * HID);
            acc += gp.x * wa;
            acc += gp.y * wb;
        }
        acc.x += __shfl_xor(acc.x, 16);
        acc.y += __shfl_xor(acc.y, 16);
        float wsr = r ? wsB : wsA;
        if (node < N && s == 0) {
            v2f bb2 = *(const v2f*)(sb2 + oc2 * 2);
            v2f res = (acc + wsr * bb2) * (1.0f / DEG);
            *(v2f*)(out + (size_t)node * HID + oc2 * 2) = res;  // 128 B per node
        }
    }
}

// Fallback if d_ws too small (needs N*192 bytes): single fused kernel.
__global__ __launch_bounds__(256) void fused_fallback(
    const float* __restrict__ x, const float* __restrict__ wgt,
    const float* __restrict__ W1, const float* __restrict__ b1,
    const float* __restrict__ W2, const float* __restrict__ b2,
    const int* __restrict__ nbr, float* __restrict__ out, int N) {
    __shared__ float sW2[HID * HID];
    __shared__ float sb2[HID];
    __shared__ int2  sp[8 * DEG];
    int t = threadIdx.x;
#pragma unroll
    for (int i = 0; i < 4; ++i) sW2[t + i * 256] = W2[t + i * 256];
    if (t < HID) sb2[t] = b2[t];
    int slot = t >> 5, hid = t & 31;
    int node = blockIdx.x * 8 + slot;
    bool valid = node < N;
    int nc = valid ? node : (N - 1);
    int   j_own = nbr[nc * DEG + hid];
    float w_own = wgt[j_own];
    sp[slot * DEG + hid] = make_int2(j_own * (CIN * 4), __float_as_int(w_own));
    const float4* xip = (const float4*)(x + (size_t)nc * CIN);
    float4 xa = xip[0], xb = xip[1];
    float w1t[8];
#pragma unroll
    for (int k = 0; k < 8; ++k) w1t[k] = W1[k * HID + hid];
    float vb = b1[hid];
    vb = fmaf(xa.x, W1[ 8 * HID + hid], vb);
    vb = fmaf(xa.y, W1[ 9 * HID + hid], vb);
    vb = fmaf(xa.z, W1[10 * HID + hid], vb);
    vb = fmaf(xa.w, W1[11 * HID + hid], vb);
    vb = fmaf(xb.x, W1[12 * HID + hid], vb);
    vb = fmaf(xb.y, W1[13 * HID + hid], vb);
    vb = fmaf(xb.z, W1[14 * HID + hid], vb);
    vb = fmaf(xb.w, W1[15 * HID + hid], vb);
    float ws = w_own;
    ws += __shfl_xor(ws, 1);  ws += __shfl_xor(ws, 2);
    ws += __shfl_xor(ws, 4);  ws += __shfl_xor(ws, 8);
    ws += __shfl_xor(ws, 16);
    __syncthreads();
    const char* xbytes = (const char*)x;
    const int2* myp = &sp[slot * DEG];
    float g = 0.f;
#pragma unroll 8
    for (int e = 0; e < DEG; ++e) {
        int2  p  = myp[e];
        float wjv = __int_as_float(p.y);
        const float4* xjp = (const float4*)(xbytes + (unsigned)p.x);
        float4 a = xjp[0], b = xjp[1];
        float tin = vb;
        tin = fmaf(a.x, w1t[0], tin); tin = fmaf(a.y, w1t[1], tin);
        tin = fmaf(a.z, w1t[2], tin); tin = fmaf(a.w, w1t[3], tin);
        tin = fmaf(b.x, w1t[4], tin); tin = fmaf(b.y, w1t[5], tin);
        tin = fmaf(b.z, w1t[6], tin); tin = fmaf(b.w, w1t[7], tin);
        float x2 = tin * tin;
        float z  = tin * fmaf(GELU_B, x2, GELU_A);
        float e2 = __builtin_amdgcn_exp2f(z);
        float r  = __builtin_amdgcn_rcpf(1.0f + e2);
        g = fmaf(wjv, fmaf(-tin, r, tin), g);
    }
    float acc = 0.f;
#pragma unroll
    for (int h = 0; h < HID; ++h) {
        float gh = __shfl(g, h, 32);
        acc = fmaf(gh, sW2[h * HID + hid], acc);
    }
    if (valid) out[(size_t)node * HID + hid] = fmaf(ws, sb2[hid], acc) * (1.0f / DEG);
}

extern "C" void kernel_launch(void* const* d_in, const int* in_sizes, int n_in,
                              void* d_out, int out_size, void* d_ws, size_t ws_size,
                              hipStream_t stream) {
    const float* x   = (const float*)d_in[0];
    const float* wq  = (const float*)d_in[1];
    const float* W1  = (const float*)d_in[2];
    const float* b1  = (const float*)d_in[3];
    const float* W2  = (const float*)d_in[4];
    const float* b2  = (const float*)d_in[5];
    const int*   nbr = (const int*)d_in[6];
    float* out = (float*)d_out;

    int N = in_sizes[1];                       // in_weights has N elements
    size_t need = (size_t)N * (64 + 128);      // u16 (64 B) + v32 (128 B) per node

    if (ws_size >= need) {
        unsigned* u16 = (unsigned*)d_ws;
        float*    v32 = (float*)((char*)d_ws + (size_t)N * 64);
        int blocks_pre = (N * 4 + 255) / 256;
        precompute_uv16<<<blocks_pre, 256, 0, stream>>>(x, W1, b1, u16, v32, N);
        int blocks_main = (N + 15) / 16;       // 16 nodes per 256-thread block
        git_main5<<<blocks_main, 256, 0, stream>>>(u16, v32, wq, W2, b2, nbr, out, N);
    } else {
        int blocks = (N + 7) / 8;
        fused_fallback<<<blocks, 256, 0, stream>>>(x, wq, W1, b1, W2, b2, nbr, out, N);
    }
}

// Round 8
// 131.060 us; speedup vs baseline: 1.0509x; 1.0509x over previous
//
#include <hip/hip_runtime.h>

#define DEG 32
#define HID 32
#define CIN 8

typedef float v2f __attribute__((ext_vector_type(2)));

// gelu(x) = x - x * rcp(1 + exp2( x*(A + B*x^2) ))   [jax tanh-approx, refactored]
#define GELU_A ((float)(2.0 * 1.4426950408889634 * 0.7978845608028654))
#define GELU_B ((float)(2.0 * 1.4426950408889634 * 0.7978845608028654 * 0.044715))

__device__ __forceinline__ unsigned f2bf(float f) {   // fp32 -> bf16 (RNE)
    unsigned b = __float_as_uint(f);
    return (b + 0x7fffu + ((b >> 16) & 1u)) >> 16;
}

// Phase 1: u16[n] = bf16(x[n] @ W1[:8])  (row = 64 B)  and
//          v32[n] = fp32(b1 + x[n] @ W1[8:])  (row = 128 B).
__global__ __launch_bounds__(256) void precompute_uv16(
    const float* __restrict__ x, const float* __restrict__ W1,
    const float* __restrict__ b1, unsigned* __restrict__ u16,
    float* __restrict__ v32, int N) {
    int tid = blockIdx.x * 256 + threadIdx.x;
    if (tid >= N * 4) return;
    int n = tid >> 2;
    int q = tid & 3;                        // channels q*8 .. q*8+7
    const float4* xp = (const float4*)(x + (size_t)n * CIN);
    float4 a = xp[0], b = xp[1];
    float xv[8] = {a.x, a.y, a.z, a.w, b.x, b.y, b.z, b.w};
    float4 b1a = *(const float4*)(b1 + q * 8);
    float4 b1b = *(const float4*)(b1 + q * 8 + 4);
    float su[8] = {0.f, 0.f, 0.f, 0.f, 0.f, 0.f, 0.f, 0.f};
    float sv[8] = {b1a.x, b1a.y, b1a.z, b1a.w, b1b.x, b1b.y, b1b.z, b1b.w};
#pragma unroll
    for (int k = 0; k < 8; ++k) {
        float4 u0 = *(const float4*)(W1 + k * HID + q * 8);
        float4 u1 = *(const float4*)(W1 + k * HID + q * 8 + 4);
        float4 v0 = *(const float4*)(W1 + (k + 8) * HID + q * 8);
        float4 v1 = *(const float4*)(W1 + (k + 8) * HID + q * 8 + 4);
        float xk = xv[k];
        su[0] = fmaf(xk, u0.x, su[0]); su[1] = fmaf(xk, u0.y, su[1]);
        su[2] = fmaf(xk, u0.z, su[2]); su[3] = fmaf(xk, u0.w, su[3]);
        su[4] = fmaf(xk, u1.x, su[4]); su[5] = fmaf(xk, u1.y, su[5]);
        su[6] = fmaf(xk, u1.z, su[6]); su[7] = fmaf(xk, u1.w, su[7]);
        sv[0] = fmaf(xk, v0.x, sv[0]); sv[1] = fmaf(xk, v0.y, sv[1]);
        sv[2] = fmaf(xk, v0.z, sv[2]); sv[3] = fmaf(xk, v0.w, sv[3]);
        sv[4] = fmaf(xk, v1.x, sv[4]); sv[5] = fmaf(xk, v1.y, sv[5]);
        sv[6] = fmaf(xk, v1.z, sv[6]); sv[7] = fmaf(xk, v1.w, sv[7]);
    }
    uint4 o;
    o.x = f2bf(su[0]) | (f2bf(su[1]) << 16);
    o.y = f2bf(su[2]) | (f2bf(su[3]) << 16);
    o.z = f2bf(su[4]) | (f2bf(su[5]) << 16);
    o.w = f2bf(su[6]) | (f2bf(su[7]) << 16);
    *(uint4*)(u16 + (size_t)n * 16 + q * 4) = o;
    *(float4*)(v32 + (size_t)n * HID + q * 8)     = make_float4(sv[0], sv[1], sv[2], sv[3]);
    *(float4*)(v32 + (size_t)n * HID + q * 8 + 4) = make_float4(sv[4], sv[5], sv[6], sv[7]);
}

// Phase 2: half-wave per node (8 nodes / 256-block) — R6 structure (best), with
// the 4 per-iteration reciprocals batched into ONE v_rcp_f32 via the product
// trick (trans-pipe 2.0 -> 1.25 ops/element). z clamped at 31 so the 4-way
// product can't overflow (gelu delta < 2^-31 * |x| where clamp engages).
__global__ __launch_bounds__(256, 8) void git_main6(
    const unsigned* __restrict__ u16, const float* __restrict__ v32,
    const float* __restrict__ wgt, const float* __restrict__ W2,
    const float* __restrict__ b2, const int* __restrict__ nbr,
    float* __restrict__ out, int N) {
    __shared__ float sW2[HID * HID];
    __shared__ float sb2[HID];
    __shared__ int2  sp[8 * 33];       // 8 node slots x 32 edges, stride 33 (bank pad)
    __shared__ float sg[8 * HID];      // per-slot reduced g

    int t = threadIdx.x;
#pragma unroll
    for (int i = 0; i < 4; ++i) sW2[t + i * 256] = W2[t + i * 256];
    if (t < HID) sb2[t] = b2[t];

    int slot = t >> 5;                 // node slot 0..7
    int l5   = t & 31;
    int ep   = l5 >> 3;                // edge group
    int c4   = l5 & 7;                 // channel quad: channels 4c4..4c4+3
    int node = blockIdx.x * 8 + slot;
    bool valid = node < N;
    int nc = valid ? node : (N - 1);

    // stage (u-row byte offset, weight) for edge l5  (wave-internal LDS)
    int   j_own = nbr[nc * DEG + l5];              // coalesced
    float w_own = wgt[j_own];                      // 400 KB table, cache-hot
    sp[slot * 33 + l5] = make_int2(j_own << 6, __float_as_int(w_own));

    // ws = sum of 32 neighbor weights (butterfly within the half)
    float ws = w_own;
    ws += __shfl_xor(ws, 1);  ws += __shfl_xor(ws, 2);
    ws += __shfl_xor(ws, 4);  ws += __shfl_xor(ws, 8);
    ws += __shfl_xor(ws, 16);

    // v for this lane's 4 channels: one dwordx4 from the precomputed table
    float4 vv = *(const float4*)(v32 + (size_t)nc * HID + c4 * 4);
    v2f vb0 = {vv.x, vv.y};
    v2f vb1 = {vv.z, vv.w};

    __syncthreads();   // sW2/sb2 ready

    // ---- batched gather: 8 x (ds_read_b64 imm + add + global dwordx2) ----
    const int2* myp = &sp[slot * 33 + ep * 8];
    const char* ub  = (const char*)u16;
    int mybyte = c4 * 8;
    uint2 bits[8];
    float wj[8];
#pragma unroll
    for (int e = 0; e < 8; ++e) {
        int2 p  = myp[e];                           // imm offset e*8
        wj[e]   = __int_as_float(p.y);
        bits[e] = *(const uint2*)(ub + (unsigned)(p.x + mybyte));
    }

    // ---- packed gelu + weighted accumulate (4 channels/lane) ----
    v2f g0 = {0.f, 0.f}, g1 = {0.f, 0.f};
#pragma unroll
    for (int e = 0; e < 8; ++e) {
        unsigned ba = bits[e].x, bb = bits[e].y;
        v2f uf0, uf1;
        uf0.x = __uint_as_float(ba << 16);
        uf0.y = __uint_as_float(ba & 0xffff0000u);
        uf1.x = __uint_as_float(bb << 16);
        uf1.y = __uint_as_float(bb & 0xffff0000u);
        v2f t0 = uf0 + vb0, t1 = uf1 + vb1;
        v2f x20 = t0 * t0,  x21 = t1 * t1;
        v2f z0 = t0 * (x20 * GELU_B + GELU_A);
        v2f z1 = t1 * (x21 * GELU_B + GELU_A);
        z0.x = fminf(z0.x, 31.0f);  z0.y = fminf(z0.y, 31.0f);
        z1.x = fminf(z1.x, 31.0f);  z1.y = fminf(z1.y, 31.0f);
        v2f e0, e1;
        e0.x = __builtin_amdgcn_exp2f(z0.x);  e0.y = __builtin_amdgcn_exp2f(z0.y);
        e1.x = __builtin_amdgcn_exp2f(z1.x);  e1.y = __builtin_amdgcn_exp2f(z1.y);
        v2f d0 = e0 + 1.0f, d1 = e1 + 1.0f;
        // one rcp for all four denominators: r = 1/(d0.x d0.y d1.x d1.y)
        float q0 = d0.x * d0.y;
        float q1 = d1.x * d1.y;
        float r  = __builtin_amdgcn_rcpf(q0 * q1);
        float s0 = r * q1;                          // = 1/q0
        float s1 = r * q0;                          // = 1/q1
        v2f r0, r1;
        r0.x = s0 * d0.y;  r0.y = s0 * d0.x;        // = 1/d0.x, 1/d0.y
        r1.x = s1 * d1.y;  r1.y = s1 * d1.x;
        g0 += wj[e] * (t0 - t0 * r0);               // gelu; exact +/-inf limits
        g1 += wj[e] * (t1 - t1 * r1);
    }

    // reduce over the 4 edge groups (xor 8, 16 stay within the 32-half)
    g0.x += __shfl_xor(g0.x, 8);   g0.y += __shfl_xor(g0.y, 8);
    g1.x += __shfl_xor(g1.x, 8);   g1.y += __shfl_xor(g1.y, 8);
    g0.x += __shfl_xor(g0.x, 16);  g0.y += __shfl_xor(g0.y, 16);
    g1.x += __shfl_xor(g1.x, 16);  g1.y += __shfl_xor(g1.y, 16);

    if (l5 < 8)                      // ep==0 lanes publish the reduced g
        *(float4*)(&sg[slot * HID + c4 * 4]) = make_float4(g0.x, g0.y, g1.x, g1.y);

    __syncthreads();                 // sg ready

    // ---- hoisted second linear: acc[o-pair] = sum_h g[h]*W2[h][o-pair] ----
    int oc2 = l5 & 15;               // output pair: 2oc2, 2oc2+1
    int s   = l5 >> 4;               // h-half
    const float* sgrow  = &sg[slot * HID + s * 16];
    const float* w2base = &sW2[(s * 16) * HID + oc2 * 2];
    v2f acc = {0.f, 0.f};
#pragma unroll
    for (int hh = 0; hh < 8; ++hh) {
        v2f gp = *(const v2f*)(sgrow + hh * 2);            // broadcast, imm offset
        v2f wa = *(const v2f*)(w2base + (hh * 2) * HID);   // 2-way banks: free
        v2f wb = *(const v2f*)(w2base + (hh * 2 + 1) * HID);
        acc += gp.x * wa;
        acc += gp.y * wb;
    }
    acc.x += __shfl_xor(acc.x, 16);
    acc.y += __shfl_xor(acc.y, 16);

    if (valid && s == 0) {
        v2f bb2 = *(const v2f*)(sb2 + oc2 * 2);
        v2f res = (acc + ws * bb2) * (1.0f / DEG);
        *(v2f*)(out + (size_t)node * HID + oc2 * 2) = res;  // 128 B per node
    }
}

// Fallback if d_ws too small (needs N*192 bytes): single fused kernel.
__global__ __launch_bounds__(256) void fused_fallback(
    const float* __restrict__ x, const float* __restrict__ wgt,
    const float* __restrict__ W1, const float* __restrict__ b1,
    const float* __restrict__ W2, const float* __restrict__ b2,
    const int* __restrict__ nbr, float* __restrict__ out, int N) {
    __shared__ float sW2[HID * HID];
    __shared__ float sb2[HID];
    __shared__ int2  sp[8 * DEG];
    int t = threadIdx.x;
#pragma unroll
    for (int i = 0; i < 4; ++i) sW2[t + i * 256] = W2[t + i * 256];
    if (t < HID) sb2[t] = b2[t];
    int slot = t >> 5, hid = t & 31;
    int node = blockIdx.x * 8 + slot;
    bool valid = node < N;
    int nc = valid ? node : (N - 1);
    int   j_own = nbr[nc * DEG + hid];
    float w_own = wgt[j_own];
    sp[slot * DEG + hid] = make_int2(j_own * (CIN * 4), __float_as_int(w_own));
    const float4* xip = (const float4*)(x + (size_t)nc * CIN);
    float4 xa = xip[0], xb = xip[1];
    float w1t[8];
#pragma unroll
    for (int k = 0; k < 8; ++k) w1t[k] = W1[k * HID + hid];
    float vb = b1[hid];
    vb = fmaf(xa.x, W1[ 8 * HID + hid], vb);
    vb = fmaf(xa.y, W1[ 9 * HID + hid], vb);
    vb = fmaf(xa.z, W1[10 * HID + hid], vb);
    vb = fmaf(xa.w, W1[11 * HID + hid], vb);
    vb = fmaf(xb.x, W1[12 * HID + hid], vb);
    vb = fmaf(xb.y, W1[13 * HID + hid], vb);
    vb = fmaf(xb.z, W1[14 * HID + hid], vb);
    vb = fmaf(xb.w, W1[15 * HID + hid], vb);
    float ws = w_own;
    ws += __shfl_xor(ws, 1);  ws += __shfl_xor(ws, 2);
    ws += __shfl_xor(ws, 4);  ws += __shfl_xor(ws, 8);
    ws += __shfl_xor(ws, 16);
    __syncthreads();
    const char* xbytes = (const char*)x;
    const int2* myp = &sp[slot * DEG];
    float g = 0.f;
#pragma unroll 8
    for (int e = 0; e < DEG; ++e) {
        int2  p  = myp[e];
        float wjv = __int_as_float(p.y);
        const float4* xjp = (const float4*)(xbytes + (unsigned)p.x);
        float4 a = xjp[0], b = xjp[1];
        float tin = vb;
        tin = fmaf(a.x, w1t[0], tin); tin = fmaf(a.y, w1t[1], tin);
        tin = fmaf(a.z, w1t[2], tin); tin = fmaf(a.w, w1t[3], tin);
        tin = fmaf(b.x, w1t[4], tin); tin = fmaf(b.y, w1t[5], tin);
        tin = fmaf(b.z, w1t[6], tin); tin = fmaf(b.w, w1t[7], tin);
        float x2 = tin * tin;
        float z  = tin * fmaf(GELU_B, x2, GELU_A);
        float e2 = __builtin_amdgcn_exp2f(z);
        float r  = __builtin_amdgcn_rcpf(1.0f + e2);
        g = fmaf(wjv, fmaf(-tin, r, tin), g);
    }
    float acc = 0.f;
#pragma unroll
    for (int h = 0; h < HID; ++h) {
        float gh = __shfl(g, h, 32);
        acc = fmaf(gh, sW2[h * HID + hid], acc);
    }
    if (valid) out[(size_t)node * HID + hid] = fmaf(ws, sb2[hid], acc) * (1.0f / DEG);
}

extern "C" void kernel_launch(void* const* d_in, const int* in_sizes, int n_in,
                              void* d_out, int out_size, void* d_ws, size_t ws_size,
                              hipStream_t stream) {
    const float* x   = (const float*)d_in[0];
    const float* wq  = (const float*)d_in[1];
    const float* W1  = (const float*)d_in[2];
    const float* b1  = (const float*)d_in[3];
    const float* W2  = (const float*)d_in[4];
    const float* b2  = (const float*)d_in[5];
    const int*   nbr = (const int*)d_in[6];
    float* out = (float*)d_out;

    int N = in_sizes[1];                       // in_weights has N elements
    size_t need = (size_t)N * (64 + 128);      // u16 (64 B) + v32 (128 B) per node

    if (ws_size >= need) {
        unsigned* u16 = (unsigned*)d_ws;
        float*    v32 = (float*)((char*)d_ws + (size_t)N * 64);
        int blocks_pre = (N * 4 + 255) / 256;
        precompute_uv16<<<blocks_pre, 256, 0, stream>>>(x, W1, b1, u16, v32, N);
        int blocks_main = (N + 7) / 8;         // 8 nodes per 256-thread block
        git_main6<<<blocks_main, 256, 0, stream>>>(u16, v32, wq, W2, b2, nbr, out, N);
    } else {
        int blocks = (N + 7) / 8;
        fused_fallback<<<blocks, 256, 0, stream>>>(x, wq, W1, b1, W2, b2, nbr, out, N);
    }
}

// Round 9
// 117.432 us; speedup vs baseline: 1.1728x; 1.1161x over previous
//
#include <hip/hip_runtime.h>

#define DEG 32
#define HID 32
#define CIN 8

typedef float v2f __attribute__((ext_vector_type(2)));
typedef short bf16x8 __attribute__((ext_vector_type(8)));   // 8 bf16 = 4 VGPRs
typedef float f32x16 __attribute__((ext_vector_type(16)));  // MFMA 32x32 C/D

// gelu(x) = x - x * rcp(1 + exp2( x*(A + B*x^2) ))   [jax tanh-approx, refactored]
#define GELU_A ((float)(2.0 * 1.4426950408889634 * 0.7978845608028654))
#define GELU_B ((float)(2.0 * 1.4426950408889634 * 0.7978845608028654 * 0.044715))

__device__ __forceinline__ unsigned f2bf(float f) {   // fp32 -> bf16 (RNE)
    unsigned b = __float_as_uint(f);
    return (b + 0x7fffu + ((b >> 16) & 1u)) >> 16;
}
__device__ __forceinline__ unsigned pack2(float lo, float hi) {
    return f2bf(lo) | (f2bf(hi) << 16);
}

// Phase 1: x16[n] = bf16(x[n]) (row = 16 B -> gathered table only 1.6 MB,
// fully L2-resident per XCD) and w1f = W1 cast to bf16 in MFMA B-fragment
// order: lane l holds B[k = (l>>5)*8 + j][col = l&31], j=0..7.
__global__ __launch_bounds__(256) void precompute_xw(
    const float* __restrict__ x, const float* __restrict__ W1,
    unsigned* __restrict__ x16, unsigned* __restrict__ w1f, int N) {
    int tid = blockIdx.x * 256 + threadIdx.x;
    if (blockIdx.x == 0 && threadIdx.x < 64) {
        int l  = threadIdx.x;
        int kb = (l >> 5) * 8;
        int col = l & 31;
        uint4 o;
        o.x = pack2(W1[(kb + 0) * HID + col], W1[(kb + 1) * HID + col]);
        o.y = pack2(W1[(kb + 2) * HID + col], W1[(kb + 3) * HID + col]);
        o.z = pack2(W1[(kb + 4) * HID + col], W1[(kb + 5) * HID + col]);
        o.w = pack2(W1[(kb + 6) * HID + col], W1[(kb + 7) * HID + col]);
        *(uint4*)(w1f + l * 4) = o;
    }
    if (tid < N) {
        const float4* xp = (const float4*)(x + (size_t)tid * CIN);
        float4 a = xp[0], b = xp[1];
        uint4 o;
        o.x = pack2(a.x, a.y);  o.y = pack2(a.z, a.w);
        o.z = pack2(b.x, b.y);  o.w = pack2(b.z, b.w);
        *(uint4*)(x16 + (size_t)tid * 4) = o;
    }
}

// Phase 2: ONE WAVE PER NODE (4 nodes / 256-block). One MFMA computes the
// whole pre-gelu matrix T[32 edges x 32 hid] = [x_j ; x_i] @ W1:
//   A[m=edge][k]: lanes 0-31 (k=0..7)  = gathered x_j rows (16 B dwordx4),
//                 lanes 32-63 (k=8..15) = broadcast x_i row.
//   C-layout (HW-verified): col=lane&31 (=hid), row=(reg&3)+8*(reg>>2)+4*(lane>>5).
// Then per-lane: gelu on 16 elements, edge-weighted sum (w staged in LDS,
// indexed by the row formula), cross-half reduce, hoisted W2 epilogue.
__global__ __launch_bounds__(256) void git_mfma(
    const unsigned* __restrict__ x16, const unsigned* __restrict__ w1f,
    const float* __restrict__ wgt, const float* __restrict__ b1,
    const float* __restrict__ W2, const float* __restrict__ b2,
    const int* __restrict__ nbr, float* __restrict__ out, int N) {
    __shared__ float sW2[HID * HID];
    __shared__ float sw[4 * DEG];      // per-wave edge weights
    __shared__ float sg[4 * HID];      // per-wave reduced g

    int t = threadIdx.x;
#pragma unroll
    for (int i = 0; i < 4; ++i) sW2[t + i * 256] = W2[t + i * 256];

    int wv = t >> 6;                   // wave slot 0..3 (one node each)
    int l  = t & 63;
    int l5 = l & 31;
    int hi = l >> 5;                   // k-half / row-half selector
    int node = blockIdx.x * 4 + wv;
    int nc = node < N ? node : (N - 1);

    // edge l5: neighbor id + weight (both halves load duplicates)
    int   jn = nbr[nc * DEG + l5];               // coalesced
    float w  = wgt[jn];                          // 400 KB table, cache-hot
    if (hi == 0) sw[wv * DEG + l5] = w;

    float ws = w;                                // sum of 32 weights
    ws += __shfl_xor(ws, 1);  ws += __shfl_xor(ws, 2);
    ws += __shfl_xor(ws, 4);  ws += __shfl_xor(ws, 8);
    ws += __shfl_xor(ws, 16);

    // A fragment: one 16 B load per lane (gather x_j / broadcast x_i)
    int arow = hi ? nc : jn;
    bf16x8 af = *((const bf16x8*)x16 + arow);
    bf16x8 bf = *((const bf16x8*)w1f + l);       // B fragment (pre-swizzled W1)
    float myb1 = b1[l5];

    f32x16 acc = {};                             // zero-init C
    acc = __builtin_amdgcn_mfma_f32_32x32x16_bf16(af, bf, acc, 0, 0, 0);

    // edge weights for my 16 rows: row(i) = (i&3) + 8*(i>>2) + base, base=4*hi
    int base = hi * 4;
    const float* swp = &sw[wv * DEG + base];
    float4 wq0 = *(const float4*)(swp);          // rows base+0..3
    float4 wq1 = *(const float4*)(swp + 8);      // rows base+8..11
    float4 wq2 = *(const float4*)(swp + 16);
    float4 wq3 = *(const float4*)(swp + 24);
    float wqa[16] = {wq0.x, wq0.y, wq0.z, wq0.w,  wq1.x, wq1.y, wq1.z, wq1.w,
                     wq2.x, wq2.y, wq2.z, wq2.w,  wq3.x, wq3.y, wq3.z, wq3.w};

    // gelu + weighted row-sum over my 16 (edge,hid=l5) elements
    float g = 0.f;
#pragma unroll
    for (int i = 0; i < 16; i += 2) {
        v2f tt = {acc[i] + myb1, acc[i + 1] + myb1};
        v2f x2 = tt * tt;
        v2f zz = tt * (x2 * GELU_B + GELU_A);
        v2f ee;
        ee.x = __builtin_amdgcn_exp2f(zz.x);  ee.y = __builtin_amdgcn_exp2f(zz.y);
        v2f dd = ee + 1.0f;
        v2f rr;
        rr.x = __builtin_amdgcn_rcpf(dd.x);   rr.y = __builtin_amdgcn_rcpf(dd.y);
        v2f gl = tt - tt * rr;               // gelu; exact +/-inf limits
        g = fmaf(wqa[i],     gl.x, g);
        g = fmaf(wqa[i + 1], gl.y, g);
    }
    g += __shfl_xor(g, 32);                  // combine the two row-halves
    if (hi == 0) sg[wv * HID + l5] = g;

    __syncthreads();                         // sW2 + sg ready

    // hoisted second linear: out[o=l5] = sum_h g[h] * W2[h][o], h split by half
    const float* gp  = &sg[wv * HID + hi * 16];
    const float* w2p = &sW2[(hi * 16) * HID + l5];
    float4 g0 = *(const float4*)(gp);
    float4 g1 = *(const float4*)(gp + 4);
    float4 g2 = *(const float4*)(gp + 8);
    float4 g3 = *(const float4*)(gp + 12);
    float ga[16] = {g0.x, g0.y, g0.z, g0.w,  g1.x, g1.y, g1.z, g1.w,
                    g2.x, g2.y, g2.z, g2.w,  g3.x, g3.y, g3.z, g3.w};
    float acc2 = 0.f;
#pragma unroll
    for (int h = 0; h < 16; ++h)
        acc2 = fmaf(ga[h], w2p[h * HID], acc2);  // bank = l5: conflict-free
    acc2 += __shfl_xor(acc2, 32);

    if (node < N && hi == 0)
        out[(size_t)node * HID + l5] = fmaf(ws, b2[l5], acc2) * (1.0f / DEG);
}

// Fallback if d_ws too small (needs N*16 + 1KB): single fused kernel.
__global__ __launch_bounds__(256) void fused_fallback(
    const float* __restrict__ x, const float* __restrict__ wgt,
    const float* __restrict__ W1, const float* __restrict__ b1,
    const float* __restrict__ W2, const float* __restrict__ b2,
    const int* __restrict__ nbr, float* __restrict__ out, int N) {
    __shared__ float sW2[HID * HID];
    __shared__ float sb2[HID];
    __shared__ int2  sp[8 * DEG];
    int t = threadIdx.x;
#pragma unroll
    for (int i = 0; i < 4; ++i) sW2[t + i * 256] = W2[t + i * 256];
    if (t < HID) sb2[t] = b2[t];
    int slot = t >> 5, hid = t & 31;
    int node = blockIdx.x * 8 + slot;
    bool valid = node < N;
    int nc = valid ? node : (N - 1);
    int   j_own = nbr[nc * DEG + hid];
    float w_own = wgt[j_own];
    sp[slot * DEG + hid] = make_int2(j_own * (CIN * 4), __float_as_int(w_own));
    const float4* xip = (const float4*)(x + (size_t)nc * CIN);
    float4 xa = xip[0], xb = xip[1];
    float w1t[8];
#pragma unroll
    for (int k = 0; k < 8; ++k) w1t[k] = W1[k * HID + hid];
    float vb = b1[hid];
    vb = fmaf(xa.x, W1[ 8 * HID + hid], vb);
    vb = fmaf(xa.y, W1[ 9 * HID + hid], vb);
    vb = fmaf(xa.z, W1[10 * HID + hid], vb);
    vb = fmaf(xa.w, W1[11 * HID + hid], vb);
    vb = fmaf(xb.x, W1[12 * HID + hid], vb);
    vb = fmaf(xb.y, W1[13 * HID + hid], vb);
    vb = fmaf(xb.z, W1[14 * HID + hid], vb);
    vb = fmaf(xb.w, W1[15 * HID + hid], vb);
    float ws = w_own;
    ws += __shfl_xor(ws, 1);  ws += __shfl_xor(ws, 2);
    ws += __shfl_xor(ws, 4);  ws += __shfl_xor(ws, 8);
    ws += __shfl_xor(ws, 16);
    __syncthreads();
    const char* xbytes = (const char*)x;
    const int2* myp = &sp[slot * DEG];
    float g = 0.f;
#pragma unroll 8
    for (int e = 0; e < DEG; ++e) {
        int2  p  = myp[e];
        float wjv = __int_as_float(p.y);
        const float4* xjp = (const float4*)(xbytes + (unsigned)p.x);
        float4 a = xjp[0], b = xjp[1];
        float tin = vb;
        tin = fmaf(a.x, w1t[0], tin); tin = fmaf(a.y, w1t[1], tin);
        tin = fmaf(a.z, w1t[2], tin); tin = fmaf(a.w, w1t[3], tin);
        tin = fmaf(b.x, w1t[4], tin); tin = fmaf(b.y, w1t[5], tin);
        tin = fmaf(b.z, w1t[6], tin); tin = fmaf(b.w, w1t[7], tin);
        float x2 = tin * tin;
        float z  = tin * fmaf(GELU_B, x2, GELU_A);
        float e2 = __builtin_amdgcn_exp2f(z);
        float r  = __builtin_amdgcn_rcpf(1.0f + e2);
        g = fmaf(wjv, fmaf(-tin, r, tin), g);
    }
    float acc = 0.f;
#pragma unroll
    for (int h = 0; h < HID; ++h) {
        float gh = __shfl(g, h, 32);
        acc = fmaf(gh, sW2[h * HID + hid], acc);
    }
    if (valid) out[(size_t)node * HID + hid] = fmaf(ws, sb2[hid], acc) * (1.0f / DEG);
}

extern "C" void kernel_launch(void* const* d_in, const int* in_sizes, int n_in,
                              void* d_out, int out_size, void* d_ws, size_t ws_size,
                              hipStream_t stream) {
    const float* x   = (const float*)d_in[0];
    const float* wq  = (const float*)d_in[1];
    const float* W1  = (const float*)d_in[2];
    const float* b1  = (const float*)d_in[3];
    const float* W2  = (const float*)d_in[4];
    const float* b2  = (const float*)d_in[5];
    const int*   nbr = (const int*)d_in[6];
    float* out = (float*)d_out;

    int N = in_sizes[1];                        // in_weights has N elements
    size_t need = (size_t)N * 16 + 1024;        // x16 table + W1 fragment

    if (ws_size >= need) {
        unsigned* x16 = (unsigned*)d_ws;
        unsigned* w1f = (unsigned*)((char*)d_ws + (size_t)N * 16);
        int blocks_pre = (N + 255) / 256;
        precompute_xw<<<blocks_pre, 256, 0, stream>>>(x, W1, x16, w1f, N);
        int blocks_main = (N + 3) / 4;          // 4 nodes (waves) per block
        git_mfma<<<blocks_main, 256, 0, stream>>>(x16, w1f, wq, b1, W2, b2, nbr, out, N);
    } else {
        int blocks = (N + 7) / 8;
        fused_fallback<<<blocks, 256, 0, stream>>>(x, wq, W1, b1, W2, b2, nbr, out, N);
    }
}